// Round 6
// baseline (62.947 us; speedup 1.0000x reference)
//
#include <hip/hip_runtime.h>
#include <hip/hip_bf16.h>
#include <math.h>

typedef unsigned int u32;
typedef __fp16 f16x2 __attribute__((ext_vector_type(2)));
typedef u32 u32x4 __attribute__((ext_vector_type(4)));

#define NB    192
#define NC    32
#define TFUT  27
#define NPAIR 96                 // k_recur blocks; each handles batches b and b+96
#define BLOB_F_OFF (NB * 64)     // float offset of packed-weight blob inside ws

#if __has_builtin(__builtin_amdgcn_rcpf)
#define RCPF(x) __builtin_amdgcn_rcpf(x)
#else
#define RCPF(x) (1.0f / (x))
#endif
#if __has_builtin(__builtin_amdgcn_sqrtf)
#define SQRTF(x) __builtin_amdgcn_sqrtf(x)
#else
#define SQRTF(x) sqrtf(x)
#endif
#if __has_builtin(__builtin_amdgcn_exp2f)
#define EXP2F(x) __builtin_amdgcn_exp2f(x)
#else
#define EXP2F(x) exp2f(x)
#endif
#if __has_builtin(__builtin_amdgcn_logf)
#define LOG2F(x) __builtin_amdgcn_logf(x)
#else
#define LOG2F(x) log2f(x)
#endif

__device__ __forceinline__ u32 pk16(float lo, float hi) {
    auto v = __builtin_amdgcn_cvt_pkrtz(lo, hi);
    return __builtin_bit_cast(u32, v);
}
__device__ __forceinline__ float fdot2pk(u32 a, u32 b, float c) {
#if __has_builtin(__builtin_amdgcn_fdot2)
    return __builtin_amdgcn_fdot2(__builtin_bit_cast(f16x2, a),
                                  __builtin_bit_cast(f16x2, b), c, false);
#else
    f16x2 av = __builtin_bit_cast(f16x2, a), bv = __builtin_bit_cast(f16x2, b);
    return c + (float)av[0] * (float)bv[0] + (float)av[1] * (float)bv[1];
#endif
}
__device__ __forceinline__ float rdlf(float v, int lane) {
    return __int_as_float(__builtin_amdgcn_readlane(__float_as_int(v), lane));
}
// lanes<32 receive v from lane l+32 (z-gate); VALU op, no LDS
__device__ __forceinline__ float perm32hi(float v) {
    int x = __float_as_int(v), y = x;
    asm volatile("v_permlane32_swap_b32 %0, %1" : "+v"(x), "+v"(y));
    return __int_as_float(x);
}
__device__ __forceinline__ float sigmoid_f(float x) {
    return RCPF(1.0f + EXP2F(-1.4426950408889634f * x));
}
__device__ __forceinline__ float tanh_f(float x) {
    return __builtin_fmaf(2.0f, RCPF(1.0f + EXP2F(-2.8853900817779268f * x)), -1.0f);
}

// ---------------------------------------------------------------------------
// Kernel 1: blocks 0..191: per-batch static features; block 192: weight pack
// ---------------------------------------------------------------------------
__global__ __launch_bounds__(1024) void k_static(
    const float* __restrict__ feat,      // (192,32,64,64)
    const float* __restrict__ traj_past, // (192,3,2)
    const float* __restrict__ past_W,    // (32,6)
    const float* __restrict__ past_b,    // (32)
    const float* __restrict__ W1,        // (64,2112)
    const float* __restrict__ b1,        // (64)
    const float* __restrict__ W_ih,      // (96,9)
    const float* __restrict__ W_hh,      // (96,32)
    const float* __restrict__ b_ih,      // (96)
    const float* __restrict__ b_hh,      // (96)
    const float* __restrict__ W2,        // (32,64)
    const float* __restrict__ b2,        // (32)
    const float* __restrict__ W3,        // (6,32)
    const float* __restrict__ b3,        // (6)
    float* __restrict__ ws)
{
    const int b = blockIdx.x;
    const int t = threadIdx.x;

    if (b == NB) {
        if (t >= 64) return;
        const int l = t, m2 = l & 31;
        u32* blob = reinterpret_cast<u32*>(ws) + BLOB_F_OFF + (size_t)l * 128;
        #pragma unroll
        for (int k = 0; k < 9; ++k) {
            blob[k]     = __float_as_uint(W_ih[l * 9 + k]);
            blob[9 + k] = __float_as_uint(W_ih[(64 + m2) * 9 + k]);
        }
        #pragma unroll
        for (int j = 0; j < 16; ++j) {
            blob[18 + j] = pk16(W_hh[l * 32 + 2*j],          W_hh[l * 32 + 2*j + 1]);
            blob[34 + j] = pk16(W_hh[(64 + m2) * 32 + 2*j],  W_hh[(64 + m2) * 32 + 2*j + 1]);
            blob[50 + j] = pk16(W1[(size_t)l * 2112 + 2*j],  W1[(size_t)l * 2112 + 2*j + 1]);
        }
        #pragma unroll
        for (int j = 0; j < 32; ++j)
            blob[66 + j] = pk16(W2[m2 * 64 + 2*j], W2[m2 * 64 + 2*j + 1]);
        const int wr = (l < 6) ? l : 0;
        #pragma unroll
        for (int j = 0; j < 16; ++j)
            blob[98 + j] = pk16(W3[wr * 32 + 2*j], W3[wr * 32 + 2*j + 1]);
        blob[114] = __float_as_uint(b_ih[l]);
        blob[115] = __float_as_uint(b_hh[l]);
        blob[116] = __float_as_uint(b_ih[64 + m2]);
        blob[117] = __float_as_uint(b_hh[64 + m2]);
        blob[118] = __float_as_uint(b2[m2]);
        #pragma unroll
        for (int r = 0; r < 6; ++r) blob[119 + r] = __float_as_uint(b3[r]);
        blob[125] = blob[126] = blob[127] = 0u;
        return;
    }

    __shared__ __align__(16) float sta[2080];

    for (int it = 0; it < 2; ++it) {
        const int c    = it * 16 + (t >> 6);
        const int cell = t & 63;
        const int zi = cell >> 3, xi = cell & 7;
        const float* p = feat + ((size_t)b * NC + c) * 4096 + zi * 8 * 64 + xi * 8;
        float m = -3.402823466e38f;
        #pragma unroll
        for (int dz = 0; dz < 8; ++dz) {
            const float4 v0 = *reinterpret_cast<const float4*>(p + dz * 64);
            const float4 v1 = *reinterpret_cast<const float4*>(p + dz * 64 + 4);
            m = fmaxf(m, fmaxf(fmaxf(fmaxf(v0.x, v0.y), fmaxf(v0.z, v0.w)),
                               fmaxf(fmaxf(v1.x, v1.y), fmaxf(v1.z, v1.w))));
        }
        sta[c * 64 + cell] = m;
    }
    if (t < 32) {
        float acc = past_b[t];
        #pragma unroll
        for (int k = 0; k < 6; ++k) acc += past_W[t * 6 + k] * traj_past[b * 6 + k];
        sta[2048 + t] = acc;
    }
    __syncthreads();

    const int o = t >> 4, l = t & 15;
    const float* wrow = W1 + (size_t)o * 2112 + 32;
    float acc = 0.f;
    #pragma unroll 4
    for (int j = 0; j < 32; ++j) {
        const int k = j * 64 + l * 4;
        const float4 w = *reinterpret_cast<const float4*>(wrow + k);
        const float4 s = *reinterpret_cast<const float4*>(&sta[k]);
        acc += w.x * s.x + w.y * s.y + w.z * s.z + w.w * s.w;
    }
    if (l < 8) {
        const int k = 2048 + l * 4;
        const float4 w = *reinterpret_cast<const float4*>(wrow + k);
        const float4 s = *reinterpret_cast<const float4*>(&sta[k]);
        acc += w.x * s.x + w.y * s.y + w.z * s.z + w.w * s.w;
    }
    acc += __shfl_xor(acc, 1);
    acc += __shfl_xor(acc, 2);
    acc += __shfl_xor(acc, 4);
    acc += __shfl_xor(acc, 8);
    if (l == 0) ws[b * 64 + o] = b1[o] + acc;
}

// ---------------------------------------------------------------------------
// Kernel 2: TWO interleaved batch recurrences per wave (phase-staggered).
// Broadcasts via in-order LDS write->b128 broadcast reads; z-gate via
// v_permlane32_swap. Weights (f16-packed blob) shared across both batches.
// ---------------------------------------------------------------------------
__global__ __launch_bounds__(64, 1) void k_recur(
    const float* __restrict__ pred_map,  // (192,1,64,64)
    const float* __restrict__ noise,     // (192,27,2)
    const float* __restrict__ traj_past, // (192,3,2)
    const float* __restrict__ ws,        // sta1 + blob
    float* __restrict__ out)             // (192,27,2)
{
    __shared__ __align__(16) float  pm[2][4096];
    __shared__ __align__(16) float  nzs[2][56];
    __shared__ __align__(16) __fp16 hxb[2][64];
    __shared__ __align__(16) __fp16 h1b[2][64];
    __shared__ __align__(16) __fp16 h2b[2][64];

    const int l = threadIdx.x;
    const int bb[2] = { (int)blockIdx.x, (int)blockIdx.x + NPAIR };

    #pragma unroll
    for (int s = 0; s < 2; ++s) {
        const float4* src = reinterpret_cast<const float4*>(pred_map + (size_t)bb[s] * 4096);
        float4* dst = reinterpret_cast<float4*>(&pm[s][0]);
        #pragma unroll
        for (int i = 0; i < 16; ++i) dst[l + i * 64] = src[l + i * 64];
        if (l < TFUT * 2) nzs[s][l] = noise[bb[s] * (TFUT * 2) + l];
    }

    const u32* blob = reinterpret_cast<const u32*>(ws) + BLOB_F_OFF + (size_t)l * 128;
    u32x4 dv[32];
    #pragma unroll
    for (int j = 0; j < 32; ++j)
        dv[j] = reinterpret_cast<const u32x4*>(blob)[j];
#define DW(i) (dv[(i) >> 2][(i) & 3])
#define DF(i) __int_as_float((int)DW(i))

    float sta1l[2] = { ws[bb[0] * 64 + l], ws[bb[1] * 64 + l] };
    float w[2][6];
    #pragma unroll
    for (int s = 0; s < 2; ++s)
        #pragma unroll
        for (int j = 0; j < 6; ++j) w[s][j] = traj_past[bb[s] * 6 + j];
    float hxp[2]  = { 0.f, 0.f };
    float Adot[2] = { 0.f, 0.f };
    float Cdot[2] = { 0.f, 0.f };

    __syncthreads();

    auto bsamp = [&](int s, float px, float pz) -> float {
        float x = (px + 16.0f) * 2.0f - 0.5f;
        float z = (pz + 16.0f) * 2.0f - 0.5f;
        x = fminf(fmaxf(x, 0.0f), 63.0f);
        z = fminf(fmaxf(z, 0.0f), 63.0f);
        const float xf = floorf(x), zf = floorf(z);
        const int x0 = (int)xf, z0 = (int)zf;
        const int x1 = min(x0 + 1, 63), z1 = min(z0 + 1, 63);
        const float wx = x - xf, wz = z - zf;
        const float v00 = pm[s][z0 * 64 + x0], v01 = pm[s][z0 * 64 + x1];
        const float v10 = pm[s][z1 * 64 + x0], v11 = pm[s][z1 * 64 + x1];
        return v00 * (1.f - wx) * (1.f - wz) + v01 * wx * (1.f - wz)
             + v10 * (1.f - wx) * wz        + v11 * wx * wz;
    };

    float sm0[2], sm1[2], sm2[2];
    #pragma unroll
    for (int s = 0; s < 2; ++s) {
        sm0[s] = bsamp(s, w[s][0], w[s][1]);
        sm1[s] = bsamp(s, w[s][2], w[s][3]);
        sm2[s] = bsamp(s, w[s][4], w[s][5]);
    }

    u32x4 hx4[2][4], h14[2][8], h24[2][4];

// ---- phase macros (S is a literal; all register-array indices constant) ----
#define GATES(S) { \
    float gi  = DF(114) + DF(3)*w[S][0] + DF(4)*w[S][1] + DF(5)*w[S][2] \
                        + DF(6)*w[S][3] + DF(7)*w[S][4] + DF(8)*w[S][5]; \
    float gi2 = DF(116) + DF(12)*w[S][0] + DF(13)*w[S][1] + DF(14)*w[S][2] \
                        + DF(15)*w[S][3] + DF(16)*w[S][4] + DF(17)*w[S][5]; \
    gi  += DF(0)*sm0[S] + DF(1)*sm1[S] + DF(2)*sm2[S]; \
    gi2 += DF(9)*sm0[S] + DF(10)*sm1[S] + DF(11)*sm2[S]; \
    const float gs = gi + DF(115) + Adot[S]; \
    const float sg = sigmoid_f(gs); \
    const float zv = perm32hi(sg); \
    const float nv = tanh_f(gi2 + sg * (DF(117) + Cdot[S])); \
    const float hn = (1.0f - zv) * nv + zv * hxp[S]; \
    hxp[S] = hn; \
    hxb[S][l] = (__fp16)hn; \
    const u32x4* _p = reinterpret_cast<const u32x4*>(&hxb[S][0]); \
    _Pragma("unroll") for (int q = 0; q < 4; ++q) hx4[S][q] = _p[q]; }

#define DOTS1(S) { \
    float A0=0.f,A1=0.f,A2=0.f,A3=0.f,C0=0.f,C1=0.f,C2=0.f,C3=0.f; \
    float D0=0.f,D1=0.f,D2=0.f,D3=0.f; \
    _Pragma("unroll") for (int q = 0; q < 4; ++q) { \
        const u32 p0 = hx4[S][q][0], p1 = hx4[S][q][1]; \
        const u32 p2 = hx4[S][q][2], p3 = hx4[S][q][3]; \
        const int j = q * 4; \
        A0 = fdot2pk(p0, DW(18+j),   A0); A1 = fdot2pk(p1, DW(19+j), A1); \
        A2 = fdot2pk(p2, DW(20+j),   A2); A3 = fdot2pk(p3, DW(21+j), A3); \
        C0 = fdot2pk(p0, DW(34+j),   C0); C1 = fdot2pk(p1, DW(35+j), C1); \
        C2 = fdot2pk(p2, DW(36+j),   C2); C3 = fdot2pk(p3, DW(37+j), C3); \
        D0 = fdot2pk(p0, DW(50+j),   D0); D1 = fdot2pk(p1, DW(51+j), D1); \
        D2 = fdot2pk(p2, DW(52+j),   D2); D3 = fdot2pk(p3, DW(53+j), D3); } \
    Adot[S] = (A0 + A1) + (A2 + A3); \
    Cdot[S] = (C0 + C1) + (C2 + C3); \
    const float h1a = sta1l[S] + ((D0 + D1) + (D2 + D3)); \
    const float h1l = (h1a >= 0.f) ? h1a : 0.01f * h1a; \
    h1b[S][l] = (__fp16)h1l; \
    const u32x4* _p = reinterpret_cast<const u32x4*>(&h1b[S][0]); \
    _Pragma("unroll") for (int q = 0; q < 8; ++q) h14[S][q] = _p[q]; }

#define DOTS2(S) { \
    float P0=0.f,P1=0.f,P2=0.f,P3=0.f,P4=0.f,P5=0.f,P6=0.f,P7=0.f; \
    _Pragma("unroll") for (int q = 0; q < 8; q += 2) { \
        const int j = q * 4; \
        P0 = fdot2pk(h14[S][q][0],   DW(66+j), P0); \
        P1 = fdot2pk(h14[S][q][1],   DW(67+j), P1); \
        P2 = fdot2pk(h14[S][q][2],   DW(68+j), P2); \
        P3 = fdot2pk(h14[S][q][3],   DW(69+j), P3); \
        P4 = fdot2pk(h14[S][q+1][0], DW(70+j), P4); \
        P5 = fdot2pk(h14[S][q+1][1], DW(71+j), P5); \
        P6 = fdot2pk(h14[S][q+1][2], DW(72+j), P6); \
        P7 = fdot2pk(h14[S][q+1][3], DW(73+j), P7); } \
    const float h2a = DF(118) + (((P0+P1)+(P2+P3)) + ((P4+P5)+(P6+P7))); \
    const float h2l = (h2a >= 0.f) ? h2a : 0.01f * h2a; \
    h2b[S][l] = (__fp16)h2l; \
    const u32x4* _p = reinterpret_cast<const u32x4*>(&h2b[S][0]); \
    _Pragma("unroll") for (int q = 0; q < 4; ++q) h24[S][q] = _p[q]; }

#define TAIL(S) { \
    float Q0=0.f,Q1=0.f,Q2=0.f,Q3=0.f; \
    _Pragma("unroll") for (int q = 0; q < 4; ++q) { \
        const int j = q * 4; \
        Q0 = fdot2pk(h24[S][q][0], DW(98+j),  Q0); \
        Q1 = fdot2pk(h24[S][q][1], DW(99+j),  Q1); \
        Q2 = fdot2pk(h24[S][q][2], DW(100+j), Q2); \
        Q3 = fdot2pk(h24[S][q][3], DW(101+j), Q3); } \
    const float praw = (Q0 + Q1) + (Q2 + Q3); \
    const float pv0 = rdlf(praw, 0) + DF(119); \
    const float pv1 = rdlf(praw, 1) + DF(120); \
    const float pv2 = rdlf(praw, 2) + DF(121); \
    const float pv3 = rdlf(praw, 3) + DF(122); \
    const float pv4 = rdlf(praw, 4) + DF(123); \
    const float pv5 = rdlf(praw, 5) + DF(124); \
    float s00 = pv2 + 1e-8f, s01 = pv3; \
    float s10 = pv4,          s11 = pv5 + 1e-8f; \
    const float nrm = SQRTF(s00*s00 + s01*s01 + s10*s10 + s11*s11); \
    const float arg = nrm * 0.2f; \
    const float mmx = fmaxf(arg, 1.0f); \
    const float dd  = fabsf(arg - 1.0f); \
    const float den = mmx + 0.6931471805599453f * \
                      LOG2F(1.0f + EXP2F(-1.4426950408889634f * dd)); \
    const float inv = RCPF(den); \
    s00 *= inv; s01 *= inv; s10 *= inv; s11 *= inv; \
    const float sig00 = s00*s00 + s01*s01; \
    const float sig01 = s00*s10 + s01*s11; \
    const float sig11 = s10*s10 + s11*s11; \
    const float xd0 = pv0 + nnv[S][0] * (sig00 + sig01); \
    const float xd1 = pv1 + nnv[S][1] * (sig01 + sig11); \
    const float nx0 = 2.0f * w[S][4] - w[S][2] + xd0; \
    const float nx1 = 2.0f * w[S][5] - w[S][3] + xd1; \
    if (l == 0) { \
        float2 o; o.x = nx0; o.y = nx1; \
        *reinterpret_cast<float2*>(out + ((size_t)bb[S] * TFUT + ts) * 2) = o; \
    } \
    w[S][0] = w[S][2]; w[S][1] = w[S][3]; \
    w[S][2] = w[S][4]; w[S][3] = w[S][5]; \
    w[S][4] = nx0;     w[S][5] = nx1; \
    sm0[S] = sm1[S]; sm1[S] = sm2[S]; \
    sm2[S] = bsamp(S, nx0, nx1); }

    for (int ts = 0; ts < TFUT; ++ts) {
        float nnv[2][2];
        nnv[0][0] = nzs[0][2*ts]; nnv[0][1] = nzs[0][2*ts + 1];
        nnv[1][0] = nzs[1][2*ts]; nnv[1][1] = nzs[1][2*ts + 1];

        GATES(0)
        GATES(1)
        DOTS1(0)
        DOTS1(1)
        DOTS2(0)
        DOTS2(1)
        TAIL(0)
        TAIL(1)
    }
#undef GATES
#undef DOTS1
#undef DOTS2
#undef TAIL
#undef DW
#undef DF
}

// ---------------------------------------------------------------------------
extern "C" void kernel_launch(void* const* d_in, const int* in_sizes, int n_in,
                              void* d_out, int out_size, void* d_ws, size_t ws_size,
                              hipStream_t stream) {
    const float* feat      = (const float*)d_in[0];
    const float* pred_map  = (const float*)d_in[1];
    const float* noise     = (const float*)d_in[2];
    const float* traj_past = (const float*)d_in[3];
    const float* W_ih      = (const float*)d_in[4];
    const float* W_hh      = (const float*)d_in[5];
    const float* b_ih      = (const float*)d_in[6];
    const float* b_hh      = (const float*)d_in[7];
    const float* past_W    = (const float*)d_in[8];
    const float* past_b    = (const float*)d_in[9];
    const float* W1        = (const float*)d_in[10];
    const float* b1        = (const float*)d_in[11];
    const float* W2        = (const float*)d_in[12];
    const float* b2        = (const float*)d_in[13];
    const float* W3        = (const float*)d_in[14];
    const float* b3        = (const float*)d_in[15];
    float* outp = (float*)d_out;
    float* ws   = (float*)d_ws;   // sta1 (48 KB) + weight blob (32 KB)

    k_static<<<dim3(NB + 1), dim3(1024), 0, stream>>>(
        feat, traj_past, past_W, past_b, W1, b1,
        W_ih, W_hh, b_ih, b_hh, W2, b2, W3, b3, ws);
    k_recur<<<dim3(NPAIR), dim3(64), 0, stream>>>(pred_map, noise, traj_past, ws, outp);
}

// Round 7
// 45.913 us; speedup vs baseline: 1.3710x; 1.3710x over previous
//
#include <hip/hip_runtime.h>
#include <hip/hip_bf16.h>
#include <math.h>

typedef unsigned int u32;
typedef __fp16 f16x2 __attribute__((ext_vector_type(2)));
typedef u32 u32x4 __attribute__((ext_vector_type(4)));

#define NB    192
#define NC    32
#define TFUT  27
#define BLOB_F_OFF (NB * 64)     // float offset of packed-weight blob inside ws

#if __has_builtin(__builtin_amdgcn_rcpf)
#define RCPF(x) __builtin_amdgcn_rcpf(x)
#else
#define RCPF(x) (1.0f / (x))
#endif
#if __has_builtin(__builtin_amdgcn_sqrtf)
#define SQRTF(x) __builtin_amdgcn_sqrtf(x)
#else
#define SQRTF(x) sqrtf(x)
#endif
#if __has_builtin(__builtin_amdgcn_exp2f)
#define EXP2F(x) __builtin_amdgcn_exp2f(x)
#else
#define EXP2F(x) exp2f(x)
#endif
#if __has_builtin(__builtin_amdgcn_logf)
#define LOG2F(x) __builtin_amdgcn_logf(x)
#else
#define LOG2F(x) log2f(x)
#endif

__device__ __forceinline__ u32 pk16(float lo, float hi) {
    auto v = __builtin_amdgcn_cvt_pkrtz(lo, hi);
    return __builtin_bit_cast(u32, v);
}
__device__ __forceinline__ float fdot2pk(u32 a, u32 b, float c) {
#if __has_builtin(__builtin_amdgcn_fdot2)
    return __builtin_amdgcn_fdot2(__builtin_bit_cast(f16x2, a),
                                  __builtin_bit_cast(f16x2, b), c, false);
#else
    f16x2 av = __builtin_bit_cast(f16x2, a), bv = __builtin_bit_cast(f16x2, b);
    return c + (float)av[0] * (float)bv[0] + (float)av[1] * (float)bv[1];
#endif
}
__device__ __forceinline__ u32 rdl(u32 v, int lane) {
    return (u32)__builtin_amdgcn_readlane((int)v, lane);
}
__device__ __forceinline__ float rdlf(float v, int lane) {
    return __int_as_float(__builtin_amdgcn_readlane(__float_as_int(v), lane));
}
// lane l <- lane l^1 via DPP quad_perm(1,0,3,2) — pure VALU
__device__ __forceinline__ float dpp_xor1(float v) {
    return __int_as_float(__builtin_amdgcn_update_dpp(
        0, __float_as_int(v), 0xB1, 0xF, 0xF, true));
}
// lanes<32 receive value from lane l+32 — VALU, no LDS
__device__ __forceinline__ float perm32hi(float v) {
    int x = __float_as_int(v), y = x;
    asm volatile("v_permlane32_swap_b32 %0, %1" : "+v"(x), "+v"(y));
    return __int_as_float(x);
}
__device__ __forceinline__ float sigmoid_f(float x) {
    return RCPF(1.0f + EXP2F(-1.4426950408889634f * x));
}
__device__ __forceinline__ float tanh_f(float x) {
    return __builtin_fmaf(2.0f, RCPF(1.0f + EXP2F(-2.8853900817779268f * x)), -1.0f);
}

// ---------------------------------------------------------------------------
// Kernel 1: blocks 0..191: per-batch static features; block 192: weight pack
// ---------------------------------------------------------------------------
__global__ __launch_bounds__(1024) void k_static(
    const float* __restrict__ feat,      // (192,32,64,64)
    const float* __restrict__ traj_past, // (192,3,2)
    const float* __restrict__ past_W,    // (32,6)
    const float* __restrict__ past_b,    // (32)
    const float* __restrict__ W1,        // (64,2112)
    const float* __restrict__ b1,        // (64)
    const float* __restrict__ W_ih,      // (96,9)
    const float* __restrict__ W_hh,      // (96,32)
    const float* __restrict__ b_ih,      // (96)
    const float* __restrict__ b_hh,      // (96)
    const float* __restrict__ W2,        // (32,64)
    const float* __restrict__ b2,        // (32)
    const float* __restrict__ W3,        // (6,32)
    const float* __restrict__ b3,        // (6)
    float* __restrict__ ws)
{
    const int b = blockIdx.x;
    const int t = threadIdx.x;

    if (b == NB) {
        if (t >= 64) return;
        const int l = t, m2 = l & 31;
        u32* blob = reinterpret_cast<u32*>(ws) + BLOB_F_OFF + (size_t)l * 128;
        #pragma unroll
        for (int k = 0; k < 9; ++k) {
            blob[k]     = __float_as_uint(W_ih[l * 9 + k]);
            blob[9 + k] = __float_as_uint(W_ih[(64 + m2) * 9 + k]);
        }
        #pragma unroll
        for (int j = 0; j < 16; ++j) {
            blob[18 + j] = pk16(W_hh[l * 32 + 2*j],          W_hh[l * 32 + 2*j + 1]);
            blob[34 + j] = pk16(W_hh[(64 + m2) * 32 + 2*j],  W_hh[(64 + m2) * 32 + 2*j + 1]);
            blob[50 + j] = pk16(W1[(size_t)l * 2112 + 2*j],  W1[(size_t)l * 2112 + 2*j + 1]);
        }
        #pragma unroll
        for (int j = 0; j < 32; ++j)
            blob[66 + j] = pk16(W2[m2 * 64 + 2*j], W2[m2 * 64 + 2*j + 1]);
        const int wr = (l < 6) ? l : 0;
        #pragma unroll
        for (int j = 0; j < 16; ++j)
            blob[98 + j] = pk16(W3[wr * 32 + 2*j], W3[wr * 32 + 2*j + 1]);
        blob[114] = __float_as_uint(b_ih[l]);
        blob[115] = __float_as_uint(b_hh[l]);
        blob[116] = __float_as_uint(b_ih[64 + m2]);
        blob[117] = __float_as_uint(b_hh[64 + m2]);
        blob[118] = __float_as_uint(b2[m2]);
        #pragma unroll
        for (int r = 0; r < 6; ++r) blob[119 + r] = __float_as_uint(b3[r]);
        blob[125] = blob[126] = blob[127] = 0u;
        return;
    }

    __shared__ __align__(16) float sta[2080];

    for (int it = 0; it < 2; ++it) {
        const int c    = it * 16 + (t >> 6);
        const int cell = t & 63;
        const int zi = cell >> 3, xi = cell & 7;
        const float* p = feat + ((size_t)b * NC + c) * 4096 + zi * 8 * 64 + xi * 8;
        float m = -3.402823466e38f;
        #pragma unroll
        for (int dz = 0; dz < 8; ++dz) {
            const float4 v0 = *reinterpret_cast<const float4*>(p + dz * 64);
            const float4 v1 = *reinterpret_cast<const float4*>(p + dz * 64 + 4);
            m = fmaxf(m, fmaxf(fmaxf(fmaxf(v0.x, v0.y), fmaxf(v0.z, v0.w)),
                               fmaxf(fmaxf(v1.x, v1.y), fmaxf(v1.z, v1.w))));
        }
        sta[c * 64 + cell] = m;
    }
    if (t < 32) {
        float acc = past_b[t];
        #pragma unroll
        for (int k = 0; k < 6; ++k) acc += past_W[t * 6 + k] * traj_past[b * 6 + k];
        sta[2048 + t] = acc;
    }
    __syncthreads();

    const int o = t >> 4, l = t & 15;
    const float* wrow = W1 + (size_t)o * 2112 + 32;
    float acc = 0.f;
    #pragma unroll 4
    for (int j = 0; j < 32; ++j) {
        const int k = j * 64 + l * 4;
        const float4 w = *reinterpret_cast<const float4*>(wrow + k);
        const float4 s = *reinterpret_cast<const float4*>(&sta[k]);
        acc += w.x * s.x + w.y * s.y + w.z * s.z + w.w * s.w;
    }
    if (l < 8) {
        const int k = 2048 + l * 4;
        const float4 w = *reinterpret_cast<const float4*>(wrow + k);
        const float4 s = *reinterpret_cast<const float4*>(&sta[k]);
        acc += w.x * s.x + w.y * s.y + w.z * s.z + w.w * s.w;
    }
    acc += __shfl_xor(acc, 1);
    acc += __shfl_xor(acc, 2);
    acc += __shfl_xor(acc, 4);
    acc += __shfl_xor(acc, 8);
    if (l == 0) ws[b * 64 + o] = b1[o] + acc;
}

// ---------------------------------------------------------------------------
// Kernel 2: recurrence. One wave per batch; f16 blob weights in registers;
// broadcasts via DPP pair-pack + readlane; z-gate via v_permlane32_swap;
// next-step W_hh dots fill the bilinear-sample LDS latency window.
// ---------------------------------------------------------------------------
__global__ __launch_bounds__(64, 1) void k_recur(
    const float* __restrict__ pred_map,  // (192,1,64,64)
    const float* __restrict__ noise,     // (192,27,2)
    const float* __restrict__ traj_past, // (192,3,2)
    const float* __restrict__ ws,        // sta1 + blob
    float* __restrict__ out)             // (192,27,2)
{
    __shared__ __align__(16) float pm[4096];

    const int b = blockIdx.x;
    const int l = threadIdx.x;

    // ---- stage pred_map into LDS; noise into a lane-resident VGPR ----
    {
        const float4* src = reinterpret_cast<const float4*>(pred_map + (size_t)b * 4096);
        float4* dst = reinterpret_cast<float4*>(pm);
        #pragma unroll
        for (int i = 0; i < 16; ++i) dst[l + i * 64] = src[l + i * 64];
    }
    const float nzreg = (l < TFUT * 2) ? noise[b * (TFUT * 2) + l] : 0.f;

    // ---- coalesced weight-blob load: 32 x dwordx4 per lane ----
    const u32* blob = reinterpret_cast<const u32*>(ws) + BLOB_F_OFF + (size_t)l * 128;
    u32x4 dv[32];
    #pragma unroll
    for (int j = 0; j < 32; ++j)
        dv[j] = reinterpret_cast<const u32x4*>(blob)[j];
#define DW(i) (dv[(i) >> 2][(i) & 3])
#define DF(i) __int_as_float((int)DW(i))

    const float sta1l = ws[b * 64 + l];

    float w[6];
    #pragma unroll
    for (int j = 0; j < 6; ++j) w[j] = traj_past[b * 6 + j];
    float hxp = 0.f;
    u32 hxpk[16];
    #pragma unroll
    for (int j = 0; j < 16; ++j) hxpk[j] = 0u;
    float Adot = 0.f, Cdot = 0.f;   // W_hh·hx carried across steps (hx0 = 0)

    __syncthreads();

    auto bsamp = [&](float px, float pz) -> float {
        float x = (px + 16.0f) * 2.0f - 0.5f;
        float z = (pz + 16.0f) * 2.0f - 0.5f;
        x = fminf(fmaxf(x, 0.0f), 63.0f);
        z = fminf(fmaxf(z, 0.0f), 63.0f);
        const float xf = floorf(x), zf = floorf(z);
        const int x0 = (int)xf, z0 = (int)zf;
        const int x1 = min(x0 + 1, 63), z1 = min(z0 + 1, 63);
        const float wx = x - xf, wz = z - zf;
        const float v00 = pm[z0 * 64 + x0], v01 = pm[z0 * 64 + x1];
        const float v10 = pm[z1 * 64 + x0], v11 = pm[z1 * 64 + x1];
        return v00 * (1.f - wx) * (1.f - wz) + v01 * wx * (1.f - wz)
             + v10 * (1.f - wx) * wz        + v11 * wx * wz;
    };
    float sm0 = bsamp(w[0], w[1]);
    float sm1 = bsamp(w[2], w[3]);
    float sm2 = bsamp(w[4], w[5]);

    for (int ts = 0; ts < TFUT; ++ts) {
        // ---- GATES: window terms first, fresh-sample terms last ----
        float gi  = DF(114) + DF(3) * w[0] + DF(4) * w[1] + DF(5) * w[2]
                            + DF(6) * w[3] + DF(7) * w[4] + DF(8) * w[5];
        float gi2 = DF(116) + DF(12) * w[0] + DF(13) * w[1] + DF(14) * w[2]
                            + DF(15) * w[3] + DF(16) * w[4] + DF(17) * w[5];
        gi  += DF(0) * sm0 + DF(1) * sm1 + DF(2) * sm2;
        gi2 += DF(9) * sm0 + DF(10) * sm1 + DF(11) * sm2;

        const float gs = gi + DF(115) + Adot;      // r (l<32) / z (l>=32)
        const float sg = sigmoid_f(gs);
        const float zv = perm32hi(sg);             // z for lanes<32 (VALU)
        const float nv = tanh_f(gi2 + sg * (DF(117) + Cdot));
        const float hn = (1.0f - zv) * nv + zv * hxp;   // valid l<32
        hxp = hn;

        // ---- broadcast hx ----
        const u32 hpk = pk16(hn, dpp_xor1(hn));
        #pragma unroll
        for (int j = 0; j < 16; ++j) hxpk[j] = rdl(hpk, 2 * j);

        // ---- h1[l] = leaky(sta1[l] + W1[l,:32] @ hx) ----
        float D0 = 0.f, D1 = 0.f, D2 = 0.f, D3 = 0.f;
        #pragma unroll
        for (int j = 0; j < 16; j += 4) {
            D0 = fdot2pk(hxpk[j],   DW(50 + j),     D0);
            D1 = fdot2pk(hxpk[j+1], DW(50 + j + 1), D1);
            D2 = fdot2pk(hxpk[j+2], DW(50 + j + 2), D2);
            D3 = fdot2pk(hxpk[j+3], DW(50 + j + 3), D3);
        }
        const float h1a = sta1l + ((D0 + D1) + (D2 + D3));
        const float h1l = (h1a >= 0.f) ? h1a : 0.01f * h1a;

        // ---- broadcast h1 (32 pairs) ----
        const u32 h1p = pk16(h1l, dpp_xor1(h1l));
        u32 h1pk[32];
        #pragma unroll
        for (int j = 0; j < 32; ++j) h1pk[j] = rdl(h1p, 2 * j);

        // ---- h2[m] = leaky(b2[m] + W2[m,:] @ h1), 8 accumulators ----
        float P0 = 0.f, P1 = 0.f, P2 = 0.f, P3 = 0.f;
        float P4 = 0.f, P5 = 0.f, P6 = 0.f, P7 = 0.f;
        #pragma unroll
        for (int j = 0; j < 32; j += 8) {
            P0 = fdot2pk(h1pk[j],   DW(66 + j),     P0);
            P1 = fdot2pk(h1pk[j+1], DW(66 + j + 1), P1);
            P2 = fdot2pk(h1pk[j+2], DW(66 + j + 2), P2);
            P3 = fdot2pk(h1pk[j+3], DW(66 + j + 3), P3);
            P4 = fdot2pk(h1pk[j+4], DW(66 + j + 4), P4);
            P5 = fdot2pk(h1pk[j+5], DW(66 + j + 5), P5);
            P6 = fdot2pk(h1pk[j+6], DW(66 + j + 6), P6);
            P7 = fdot2pk(h1pk[j+7], DW(66 + j + 7), P7);
        }
        const float h2a = DF(118) + (((P0 + P1) + (P2 + P3)) + ((P4 + P5) + (P6 + P7)));
        const float h2l = (h2a >= 0.f) ? h2a : 0.01f * h2a;

        // ---- broadcast h2; W3 dots (rows 0..5 meaningful) ----
        const u32 h2p = pk16(h2l, dpp_xor1(h2l));
        u32 h2pk[16];
        #pragma unroll
        for (int j = 0; j < 16; ++j) h2pk[j] = rdl(h2p, 2 * j);

        float Q0 = 0.f, Q1 = 0.f, Q2 = 0.f, Q3 = 0.f;
        #pragma unroll
        for (int j = 0; j < 16; j += 4) {
            Q0 = fdot2pk(h2pk[j],   DW(98 + j),     Q0);
            Q1 = fdot2pk(h2pk[j+1], DW(98 + j + 1), Q1);
            Q2 = fdot2pk(h2pk[j+2], DW(98 + j + 2), Q2);
            Q3 = fdot2pk(h2pk[j+3], DW(98 + j + 3), Q3);
        }
        const float praw = (Q0 + Q1) + (Q2 + Q3);

        const float pv0 = rdlf(praw, 0) + DF(119);
        const float pv1 = rdlf(praw, 1) + DF(120);
        const float pv2 = rdlf(praw, 2) + DF(121);
        const float pv3 = rdlf(praw, 3) + DF(122);
        const float pv4 = rdlf(praw, 4) + DF(123);
        const float pv5 = rdlf(praw, 5) + DF(124);

        // ---- softclip: S·S^T products branch off BEFORE the log/exp chain ----
        const float s00 = pv2 + 1e-8f, s01 = pv3;
        const float s10 = pv4,          s11 = pv5 + 1e-8f;
        const float p00 = s00 * s00 + s01 * s01;
        const float p01 = s00 * s10 + s01 * s11;   // == sig10 (pre-scale)
        const float p11 = s10 * s10 + s11 * s11;
        const float nrm = SQRTF(p00 + p11);        // ||S||_F
        const float arg = nrm * 0.2f;
        const float mmx = fmaxf(arg, 1.0f);
        const float dd  = fabsf(arg - 1.0f);
        const float den = mmx + 0.6931471805599453f *
                          LOG2F(1.0f + EXP2F(-1.4426950408889634f * dd));
        const float inv  = RCPF(den);
        const float inv2 = inv * inv;

        const float nnx = rdlf(nzreg, 2 * ts);
        const float nny = rdlf(nzreg, 2 * ts + 1);
        const float xd0 = pv0 + nnx * ((p00 + p01) * inv2);
        const float xd1 = pv1 + nny * ((p01 + p11) * inv2);
        const float nx0 = 2.0f * w[4] - w[2] + xd0;
        const float nx1 = 2.0f * w[5] - w[3] + xd1;

        if (l == 0) {
            float2 o; o.x = nx0; o.y = nx1;
            *reinterpret_cast<float2*>(out + ((size_t)b * TFUT + ts) * 2) = o;
        }

        w[0] = w[2]; w[1] = w[3];
        w[2] = w[4]; w[3] = w[5];
        w[4] = nx0;  w[5] = nx1;
        sm0 = sm1; sm1 = sm2;

        // ---- bilinear sample SPLIT: issue the 4 LDS reads... ----
        float v00, v01, v10, v11, wxs, wzs;
        {
            float x = (nx0 + 16.0f) * 2.0f - 0.5f;
            float z = (nx1 + 16.0f) * 2.0f - 0.5f;
            x = fminf(fmaxf(x, 0.0f), 63.0f);
            z = fminf(fmaxf(z, 0.0f), 63.0f);
            const float xf = floorf(x), zf = floorf(z);
            const int x0 = (int)xf, z0 = (int)zf;
            const int x1 = min(x0 + 1, 63), z1 = min(z0 + 1, 63);
            wxs = x - xf; wzs = z - zf;
            v00 = pm[z0 * 64 + x0]; v01 = pm[z0 * 64 + x1];
            v10 = pm[z1 * 64 + x0]; v11 = pm[z1 * 64 + x1];
        }

        // ---- ...fill the LDS latency with next step's W_hh·hx dots ----
        {
            float A0 = 0.f, A1 = 0.f, A2 = 0.f, A3 = 0.f;
            float C0 = 0.f, C1 = 0.f, C2 = 0.f, C3 = 0.f;
            #pragma unroll
            for (int j = 0; j < 16; j += 4) {
                A0 = fdot2pk(hxpk[j],   DW(18 + j),     A0);
                A1 = fdot2pk(hxpk[j+1], DW(18 + j + 1), A1);
                A2 = fdot2pk(hxpk[j+2], DW(18 + j + 2), A2);
                A3 = fdot2pk(hxpk[j+3], DW(18 + j + 3), A3);
                C0 = fdot2pk(hxpk[j],   DW(34 + j),     C0);
                C1 = fdot2pk(hxpk[j+1], DW(34 + j + 1), C1);
                C2 = fdot2pk(hxpk[j+2], DW(34 + j + 2), C2);
                C3 = fdot2pk(hxpk[j+3], DW(34 + j + 3), C3);
            }
            Adot = (A0 + A1) + (A2 + A3);
            Cdot = (C0 + C1) + (C2 + C3);
        }

        // ---- finish the interpolation ----
        sm2 = v00 * (1.f - wxs) * (1.f - wzs) + v01 * wxs * (1.f - wzs)
            + v10 * (1.f - wxs) * wzs        + v11 * wxs * wzs;
    }
#undef DW
#undef DF
}

// ---------------------------------------------------------------------------
extern "C" void kernel_launch(void* const* d_in, const int* in_sizes, int n_in,
                              void* d_out, int out_size, void* d_ws, size_t ws_size,
                              hipStream_t stream) {
    const float* feat      = (const float*)d_in[0];
    const float* pred_map  = (const float*)d_in[1];
    const float* noise     = (const float*)d_in[2];
    const float* traj_past = (const float*)d_in[3];
    const float* W_ih      = (const float*)d_in[4];
    const float* W_hh      = (const float*)d_in[5];
    const float* b_ih      = (const float*)d_in[6];
    const float* b_hh      = (const float*)d_in[7];
    const float* past_W    = (const float*)d_in[8];
    const float* past_b    = (const float*)d_in[9];
    const float* W1        = (const float*)d_in[10];
    const float* b1        = (const float*)d_in[11];
    const float* W2        = (const float*)d_in[12];
    const float* b2        = (const float*)d_in[13];
    const float* W3        = (const float*)d_in[14];
    const float* b3        = (const float*)d_in[15];
    float* outp = (float*)d_out;
    float* ws   = (float*)d_ws;   // sta1 (48 KB) + weight blob (32 KB)

    k_static<<<dim3(NB + 1), dim3(1024), 0, stream>>>(
        feat, traj_past, past_W, past_b, W1, b1,
        W_ih, W_hh, b_ih, b_hh, W2, b2, W3, b3, ws);
    k_recur<<<dim3(NB), dim3(64), 0, stream>>>(pred_map, noise, traj_past, ws, outp);
}

// Round 10
// 44.627 us; speedup vs baseline: 1.4105x; 1.0288x over previous
//
#include <hip/hip_runtime.h>
#include <hip/hip_bf16.h>
#include <math.h>

typedef unsigned int u32;
typedef __fp16 f16x2 __attribute__((ext_vector_type(2)));
typedef u32 u32x4 __attribute__((ext_vector_type(4)));

#define NB    192
#define NC    32
#define TFUT  27
#define BLOB_F_OFF (NB * 64)     // float offset of packed-weight blob inside ws

#if __has_builtin(__builtin_amdgcn_rcpf)
#define RCPF(x) __builtin_amdgcn_rcpf(x)
#else
#define RCPF(x) (1.0f / (x))
#endif
#if __has_builtin(__builtin_amdgcn_sqrtf)
#define SQRTF(x) __builtin_amdgcn_sqrtf(x)
#else
#define SQRTF(x) sqrtf(x)
#endif
#if __has_builtin(__builtin_amdgcn_exp2f)
#define EXP2F(x) __builtin_amdgcn_exp2f(x)
#else
#define EXP2F(x) exp2f(x)
#endif
#if __has_builtin(__builtin_amdgcn_logf)
#define LOG2F(x) __builtin_amdgcn_logf(x)
#else
#define LOG2F(x) log2f(x)
#endif

// compiler-level ordering for intra-wave LDS communication (free at runtime;
// HW DS pipe is in-order within a wave).
#define LDS_FENCE() asm volatile("" ::: "memory")

__device__ __forceinline__ u32 pk16(float lo, float hi) {
    auto v = __builtin_amdgcn_cvt_pkrtz(lo, hi);
    return __builtin_bit_cast(u32, v);
}
__device__ __forceinline__ float fdot2pk(u32 a, u32 b, float c) {
#if __has_builtin(__builtin_amdgcn_fdot2)
    return __builtin_amdgcn_fdot2(__builtin_bit_cast(f16x2, a),
                                  __builtin_bit_cast(f16x2, b), c, false);
#else
    f16x2 av = __builtin_bit_cast(f16x2, a), bv = __builtin_bit_cast(f16x2, b);
    return c + (float)av[0] * (float)bv[0] + (float)av[1] * (float)bv[1];
#endif
}
__device__ __forceinline__ float rdlf(float v, int lane) {
    return __int_as_float(__builtin_amdgcn_readlane(__float_as_int(v), lane));
}
// lane l <- lane l^1 via DPP quad_perm(1,0,3,2)
__device__ __forceinline__ float dpp_xor1(float v) {
    return __int_as_float(__builtin_amdgcn_update_dpp(
        0, __float_as_int(v), 0xB1, 0xF, 0xF, true));
}
// lanes<32 receive value from lane l+32.
// v_permlane32_swap_b32 dst, src: new_dst = [dst_lo|src_lo], new_src = [dst_hi|src_hi].
// RETURN OPERAND-1 (y): non-aliased regs -> y = [v_hi|v_hi] (low lanes = v[l+32]);
// aliased (x==y)       -> y = [v_hi|v_lo] (low lanes = v[l+32]).  Correct either way.
// (R8/R9 bug: returned operand-0, whose LOW lanes are the unchanged own value
// whenever the allocator does NOT coalesce x and y.)
__device__ __forceinline__ float perm32hi(float v) {
    int x = __float_as_int(v), y = x;
    asm volatile("v_permlane32_swap_b32 %0, %1" : "+v"(x), "+v"(y));
    return __int_as_float(y);
}
__device__ __forceinline__ float sigmoid_f(float x) {
    return RCPF(1.0f + EXP2F(-1.4426950408889634f * x));
}
__device__ __forceinline__ float tanh_f(float x) {
    return __builtin_fmaf(2.0f, RCPF(1.0f + EXP2F(-2.8853900817779268f * x)), -1.0f);
}

// ---------------------------------------------------------------------------
// Kernel 1: blocks 0..191: per-batch static features; block 192: weight pack
// Blob layout v2 (per lane l, m=l&31, h=l>>5):
//  [0..8] wih row l | [9..17] wih2 row 64+m | [18..33] whhp row l
//  [34..49] whh2p row 64+m | [50..65] w1ap row l (cols 0..31)
//  [66..81] w2p row m inputs h*32..+31 | [82..89] w3p row wr inputs h*16..+15
//  [90] b_ih[l] [91] b_hh[l] [92] b_ih[64+m] [93] b_hh[64+m] [94] b2[m]
//  [95..100] b3[0..5]
// ---------------------------------------------------------------------------
__global__ __launch_bounds__(1024) void k_static(
    const float* __restrict__ feat,      // (192,32,64,64)
    const float* __restrict__ traj_past, // (192,3,2)
    const float* __restrict__ past_W,    // (32,6)
    const float* __restrict__ past_b,    // (32)
    const float* __restrict__ W1,        // (64,2112)
    const float* __restrict__ b1,        // (64)
    const float* __restrict__ W_ih,      // (96,9)
    const float* __restrict__ W_hh,      // (96,32)
    const float* __restrict__ b_ih,      // (96)
    const float* __restrict__ b_hh,      // (96)
    const float* __restrict__ W2,        // (32,64)
    const float* __restrict__ b2,        // (32)
    const float* __restrict__ W3,        // (6,32)
    const float* __restrict__ b3,        // (6)
    float* __restrict__ ws)
{
    const int b = blockIdx.x;
    const int t = threadIdx.x;

    if (b == NB) {
        if (t >= 64) return;
        const int l = t, m2 = l & 31, h = l >> 5;
        u32* blob = reinterpret_cast<u32*>(ws) + BLOB_F_OFF + (size_t)l * 128;
        #pragma unroll
        for (int k = 0; k < 9; ++k) {
            blob[k]     = __float_as_uint(W_ih[l * 9 + k]);
            blob[9 + k] = __float_as_uint(W_ih[(64 + m2) * 9 + k]);
        }
        #pragma unroll
        for (int j = 0; j < 16; ++j) {
            blob[18 + j] = pk16(W_hh[l * 32 + 2*j],          W_hh[l * 32 + 2*j + 1]);
            blob[34 + j] = pk16(W_hh[(64 + m2) * 32 + 2*j],  W_hh[(64 + m2) * 32 + 2*j + 1]);
            blob[50 + j] = pk16(W1[(size_t)l * 2112 + 2*j],  W1[(size_t)l * 2112 + 2*j + 1]);
        }
        #pragma unroll
        for (int j = 0; j < 16; ++j)
            blob[66 + j] = pk16(W2[m2 * 64 + h * 32 + 2*j], W2[m2 * 64 + h * 32 + 2*j + 1]);
        const int wr = (m2 < 6) ? m2 : 0;
        #pragma unroll
        for (int j = 0; j < 8; ++j)
            blob[82 + j] = pk16(W3[wr * 32 + h * 16 + 2*j], W3[wr * 32 + h * 16 + 2*j + 1]);
        blob[90] = __float_as_uint(b_ih[l]);
        blob[91] = __float_as_uint(b_hh[l]);
        blob[92] = __float_as_uint(b_ih[64 + m2]);
        blob[93] = __float_as_uint(b_hh[64 + m2]);
        blob[94] = __float_as_uint(b2[m2]);
        #pragma unroll
        for (int r = 0; r < 6; ++r) blob[95 + r] = __float_as_uint(b3[r]);
        blob[101] = blob[102] = blob[103] = 0u;
        return;
    }

    __shared__ __align__(16) float sta[2080];

    for (int it = 0; it < 2; ++it) {
        const int c    = it * 16 + (t >> 6);
        const int cell = t & 63;
        const int zi = cell >> 3, xi = cell & 7;
        const float* p = feat + ((size_t)b * NC + c) * 4096 + zi * 8 * 64 + xi * 8;
        float m = -3.402823466e38f;
        #pragma unroll
        for (int dz = 0; dz < 8; ++dz) {
            const float4 v0 = *reinterpret_cast<const float4*>(p + dz * 64);
            const float4 v1 = *reinterpret_cast<const float4*>(p + dz * 64 + 4);
            m = fmaxf(m, fmaxf(fmaxf(fmaxf(v0.x, v0.y), fmaxf(v0.z, v0.w)),
                               fmaxf(fmaxf(v1.x, v1.y), fmaxf(v1.z, v1.w))));
        }
        sta[c * 64 + cell] = m;
    }
    if (t < 32) {
        float acc = past_b[t];
        #pragma unroll
        for (int k = 0; k < 6; ++k) acc += past_W[t * 6 + k] * traj_past[b * 6 + k];
        sta[2048 + t] = acc;
    }
    __syncthreads();

    const int o = t >> 4, l = t & 15;
    const float* wrow = W1 + (size_t)o * 2112 + 32;
    float acc = 0.f;
    #pragma unroll 4
    for (int j = 0; j < 32; ++j) {
        const int k = j * 64 + l * 4;
        const float4 w = *reinterpret_cast<const float4*>(wrow + k);
        const float4 s = *reinterpret_cast<const float4*>(&sta[k]);
        acc += w.x * s.x + w.y * s.y + w.z * s.z + w.w * s.w;
    }
    if (l < 8) {
        const int k = 2048 + l * 4;
        const float4 w = *reinterpret_cast<const float4*>(wrow + k);
        const float4 s = *reinterpret_cast<const float4*>(&sta[k]);
        acc += w.x * s.x + w.y * s.y + w.z * s.z + w.w * s.w;
    }
    acc += __shfl_xor(acc, 1);
    acc += __shfl_xor(acc, 2);
    acc += __shfl_xor(acc, 4);
    acc += __shfl_xor(acc, 8);
    if (l == 0) ws[b * 64 + o] = b1[o] + acc;
}

// ---------------------------------------------------------------------------
// Kernel 2: recurrence. One wave per batch. Broadcasts via single LDS
// round-trip (write b32 -> fence -> b128 reads); dup-split h2/W3 combined
// with perm32hi (operand-1!). Adot/Cdot of next step hidden in shadows.
// ---------------------------------------------------------------------------
__global__ __launch_bounds__(64, 1) void k_recur(
    const float* __restrict__ pred_map,  // (192,1,64,64)
    const float* __restrict__ noise,     // (192,27,2)
    const float* __restrict__ traj_past, // (192,3,2)
    const float* __restrict__ ws,        // sta1 + blob
    float* __restrict__ out)             // (192,27,2)
{
    __shared__ __align__(16) float pm[4096];
    __shared__ __align__(16) u32 hxbw[32];   // words 0..15 used
    __shared__ __align__(16) u32 h1bw[32];   // words 0..31
    __shared__ __align__(16) u32 h2bw[32];   // words 0..15 used

    const int b = blockIdx.x;
    const int l = threadIdx.x;
    const int h = l >> 5;
    const bool odd = (l & 1);

    // ---- stage pred_map into LDS; noise into a lane-resident VGPR ----
    {
        const float4* src = reinterpret_cast<const float4*>(pred_map + (size_t)b * 4096);
        float4* dst = reinterpret_cast<float4*>(pm);
        #pragma unroll
        for (int i = 0; i < 16; ++i) dst[l + i * 64] = src[l + i * 64];
    }
    const float nzreg = (l < TFUT * 2) ? noise[b * (TFUT * 2) + l] : 0.f;

    // ---- coalesced weight-blob load: 26 x dwordx4 per lane ----
    const u32* blob = reinterpret_cast<const u32*>(ws) + BLOB_F_OFF + (size_t)l * 128;
    u32x4 dv[26];
    #pragma unroll
    for (int j = 0; j < 26; ++j)
        dv[j] = reinterpret_cast<const u32x4*>(blob)[j];
#define DW(i) (dv[(i) >> 2][(i) & 3])
#define DF(i) __int_as_float((int)DW(i))

    const float sta1l = ws[b * 64 + l];

    float w[6];
    #pragma unroll
    for (int j = 0; j < 6; ++j) w[j] = traj_past[b * 6 + j];
    float hxp = 0.f;
    float Adot = 0.f, Cdot = 0.f;   // W_hh·hx carried across steps (hx0 = 0)

    __syncthreads();

    auto bsamp = [&](float px, float pz) -> float {
        float x = __builtin_fmaf(2.0f, px, 31.5f);
        float z = __builtin_fmaf(2.0f, pz, 31.5f);
        x = fminf(fmaxf(x, 0.0f), 63.0f);
        z = fminf(fmaxf(z, 0.0f), 63.0f);
        const float xf = floorf(x), zf = floorf(z);
        const int x0 = (int)xf, z0 = (int)zf;
        const int x1 = min(x0 + 1, 63), z1 = min(z0 + 1, 63);
        const float wx = x - xf, wz = z - zf;
        const float v00 = pm[z0 * 64 + x0], v01 = pm[z0 * 64 + x1];
        const float v10 = pm[z1 * 64 + x0], v11 = pm[z1 * 64 + x1];
        const float top = v00 + wx * (v01 - v00);
        const float bot = v10 + wx * (v11 - v10);
        return top + wz * (bot - top);
    };
    float sm0 = bsamp(w[0], w[1]);
    float sm1 = bsamp(w[2], w[3]);
    float sm2 = bsamp(w[4], w[5]);

    // pack-pair helper: both lanes of a pair produce pk16(v_even, v_odd)
    auto pkpair = [&](float v) -> u32 {
        const float nb = dpp_xor1(v);
        const float plo = odd ? nb : v;
        const float phi = odd ? v : nb;
        return pk16(plo, phi);
    };

    for (int ts = 0; ts < TFUT; ++ts) {
        // ---- GATES (tree-reassociated; fresh-sample terms last) ----
        float giA = DF(90) + DF(3) * w[0] + DF(4) * w[1];
        float giB = DF(5) * w[2] + DF(6) * w[3];
        float giC = DF(7) * w[4] + DF(8) * w[5];
        float giD = DF(0) * sm0 + DF(1) * sm1 + DF(2) * sm2;
        const float gi = (giA + giB) + (giC + giD);

        float gjA = DF(92) + DF(12) * w[0] + DF(13) * w[1];
        float gjB = DF(14) * w[2] + DF(15) * w[3];
        float gjC = DF(16) * w[4] + DF(17) * w[5];
        float gjD = DF(9) * sm0 + DF(10) * sm1 + DF(11) * sm2;
        const float gi2 = (gjA + gjB) + (gjC + gjD);

        const float gs = gi + DF(91) + Adot;       // r (l<32) / z (l>=32)
        const float sg = sigmoid_f(gs);
        const float zv = perm32hi(sg);             // z for lanes<32
        const float nv = tanh_f(gi2 + sg * (DF(93) + Cdot));
        const float hn = (1.0f - zv) * nv + zv * hxp;   // valid l<32
        hxp = hn;

        // ---- broadcast hx: write b32 -> fence -> 4x b128 reads ----
        hxbw[l >> 1] = pkpair(hn);
        LDS_FENCE();
        u32 hxpk[16];
        {
            const u32x4* r = reinterpret_cast<const u32x4*>(hxbw);
            const u32x4 t0 = r[0], t1 = r[1], t2 = r[2], t3 = r[3];
            #pragma unroll
            for (int q = 0; q < 4; ++q) {
                hxpk[q]      = t0[q];
                hxpk[4 + q]  = t1[q];
                hxpk[8 + q]  = t2[q];
                hxpk[12 + q] = t3[q];
            }
        }

        // ---- h1 dots + Adot (next step) interleaved ----
        float D0 = 0.f, D1 = 0.f, D2 = 0.f, D3 = 0.f;
        float A0 = 0.f, A1 = 0.f, A2 = 0.f, A3 = 0.f;
        #pragma unroll
        for (int j = 0; j < 16; j += 4) {
            D0 = fdot2pk(hxpk[j],   DW(50 + j),     D0);
            D1 = fdot2pk(hxpk[j+1], DW(50 + j + 1), D1);
            D2 = fdot2pk(hxpk[j+2], DW(50 + j + 2), D2);
            D3 = fdot2pk(hxpk[j+3], DW(50 + j + 3), D3);
            A0 = fdot2pk(hxpk[j],   DW(18 + j),     A0);
            A1 = fdot2pk(hxpk[j+1], DW(18 + j + 1), A1);
            A2 = fdot2pk(hxpk[j+2], DW(18 + j + 2), A2);
            A3 = fdot2pk(hxpk[j+3], DW(18 + j + 3), A3);
        }
        Adot = (A0 + A1) + (A2 + A3);
        const float h1a = sta1l + ((D0 + D1) + (D2 + D3));
        const float h1l = (h1a >= 0.f) ? h1a : 0.01f * h1a;

        // ---- broadcast h1 (own half: 4x b128) ----
        h1bw[l >> 1] = pkpair(h1l);
        LDS_FENCE();
        u32 h1in[16];
        {
            const u32x4* r = reinterpret_cast<const u32x4*>(h1bw + (h << 4));
            const u32x4 t0 = r[0], t1 = r[1], t2 = r[2], t3 = r[3];
            #pragma unroll
            for (int q = 0; q < 4; ++q) {
                h1in[q]      = t0[q];
                h1in[4 + q]  = t1[q];
                h1in[8 + q]  = t2[q];
                h1in[12 + q] = t3[q];
            }
        }

        // ---- Cdot (next step) in the h1-read shadow ----
        float C0 = 0.f, C1 = 0.f, C2 = 0.f, C3 = 0.f;
        #pragma unroll
        for (int j = 0; j < 16; j += 4) {
            C0 = fdot2pk(hxpk[j],   DW(34 + j),     C0);
            C1 = fdot2pk(hxpk[j+1], DW(34 + j + 1), C1);
            C2 = fdot2pk(hxpk[j+2], DW(34 + j + 2), C2);
            C3 = fdot2pk(hxpk[j+3], DW(34 + j + 3), C3);
        }
        Cdot = (C0 + C1) + (C2 + C3);

        // ---- h2: dup-split dot (lane l: inputs h*32..+31), combine via swap ----
        float P0 = 0.f, P1 = 0.f, P2 = 0.f, P3 = 0.f;
        #pragma unroll
        for (int j = 0; j < 16; j += 4) {
            P0 = fdot2pk(h1in[j],   DW(66 + j),     P0);
            P1 = fdot2pk(h1in[j+1], DW(66 + j + 1), P1);
            P2 = fdot2pk(h1in[j+2], DW(66 + j + 2), P2);
            P3 = fdot2pk(h1in[j+3], DW(66 + j + 3), P3);
        }
        const float Pown = (P0 + P1) + (P2 + P3);
        const float h2a = DF(94) + Pown + perm32hi(Pown);  // valid l<32
        const float h2l = (h2a >= 0.f) ? h2a : 0.01f * h2a;

        // ---- broadcast h2 (own half: 2x b128) ----
        h2bw[l >> 1] = pkpair(h2l);
        LDS_FENCE();
        u32 h2in[8];
        {
            const u32x4* r = reinterpret_cast<const u32x4*>(h2bw + (h << 3));
            const u32x4 t0 = r[0], t1 = r[1];
            #pragma unroll
            for (int q = 0; q < 4; ++q) {
                h2in[q]     = t0[q];
                h2in[4 + q] = t1[q];
            }
        }

        // ---- W3: dup-split (8 dots) + swap; praw valid lanes 0..5 ----
        float Q0 = 0.f, Q1 = 0.f, Q2 = 0.f, Q3 = 0.f;
        #pragma unroll
        for (int j = 0; j < 8; j += 4) {
            Q0 = fdot2pk(h2in[j],   DW(82 + j),     Q0);
            Q1 = fdot2pk(h2in[j+1], DW(82 + j + 1), Q1);
            Q2 = fdot2pk(h2in[j+2], DW(82 + j + 2), Q2);
            Q3 = fdot2pk(h2in[j+3], DW(82 + j + 3), Q3);
        }
        const float Qown = (Q0 + Q1) + (Q2 + Q3);
        const float praw = Qown + perm32hi(Qown);

        const float pv0 = rdlf(praw, 0) + DF(95);
        const float pv1 = rdlf(praw, 1) + DF(96);
        const float pv2 = rdlf(praw, 2) + DF(97);
        const float pv3 = rdlf(praw, 3) + DF(98);
        const float pv4 = rdlf(praw, 4) + DF(99);
        const float pv5 = rdlf(praw, 5) + DF(100);

        // ---- softclip (products branch off before the log/exp chain) ----
        const float s00 = pv2 + 1e-8f, s01 = pv3;
        const float s10 = pv4,          s11 = pv5 + 1e-8f;
        const float p00 = s00 * s00 + s01 * s01;
        const float p01 = s00 * s10 + s01 * s11;
        const float p11 = s10 * s10 + s11 * s11;
        const float nrm = SQRTF(p00 + p11);
        const float arg = nrm * 0.2f;
        const float mmx = fmaxf(arg, 1.0f);
        const float dd  = fabsf(arg - 1.0f);
        const float den = mmx + 0.6931471805599453f *
                          LOG2F(1.0f + EXP2F(-1.4426950408889634f * dd));
        const float inv  = RCPF(den);
        const float inv2 = inv * inv;

        const float nnx = rdlf(nzreg, 2 * ts);
        const float nny = rdlf(nzreg, 2 * ts + 1);
        const float xd0 = pv0 + nnx * ((p00 + p01) * inv2);
        const float xd1 = pv1 + nny * ((p01 + p11) * inv2);
        const float nx0 = 2.0f * w[4] - w[2] + xd0;
        const float nx1 = 2.0f * w[5] - w[3] + xd1;

        if (l == 0) {
            float2 o; o.x = nx0; o.y = nx1;
            *reinterpret_cast<float2*>(out + ((size_t)b * TFUT + ts) * 2) = o;
        }

        w[0] = w[2]; w[1] = w[3];
        w[2] = w[4]; w[3] = w[5];
        w[4] = nx0;  w[5] = nx1;
        sm0 = sm1; sm1 = sm2;
        sm2 = bsamp(nx0, nx1);   // LDS latency hidden by next-iter window FMAs
    }
#undef DW
#undef DF
}

// ---------------------------------------------------------------------------
extern "C" void kernel_launch(void* const* d_in, const int* in_sizes, int n_in,
                              void* d_out, int out_size, void* d_ws, size_t ws_size,
                              hipStream_t stream) {
    const float* feat      = (const float*)d_in[0];
    const float* pred_map  = (const float*)d_in[1];
    const float* noise     = (const float*)d_in[2];
    const float* traj_past = (const float*)d_in[3];
    const float* W_ih      = (const float*)d_in[4];
    const float* W_hh      = (const float*)d_in[5];
    const float* b_ih      = (const float*)d_in[6];
    const float* b_hh      = (const float*)d_in[7];
    const float* past_W    = (const float*)d_in[8];
    const float* past_b    = (const float*)d_in[9];
    const float* W1        = (const float*)d_in[10];
    const float* b1        = (const float*)d_in[11];
    const float* W2        = (const float*)d_in[12];
    const float* b2        = (const float*)d_in[13];
    const float* W3        = (const float*)d_in[14];
    const float* b3        = (const float*)d_in[15];
    float* outp = (float*)d_out;
    float* ws   = (float*)d_ws;   // sta1 (48 KB) + weight blob (32 KB)

    k_static<<<dim3(NB + 1), dim3(1024), 0, stream>>>(
        feat, traj_past, past_W, past_b, W1, b1,
        W_ih, W_hh, b_ih, b_hh, W2, b2, W3, b3, ws);
    k_recur<<<dim3(NB), dim3(64), 0, stream>>>(pred_map, noise, traj_past, ws, outp);
}